// Round 1
// baseline (532.233 us; speedup 1.0000x reference)
//
#include <hip/hip_runtime.h>

// EdgeSageLayer on MI355X.
// Decomposition: agg[n] = (sum_{e:dst=n} concat(x[src_e], ea_e)) @ msg_w / deg
//                         + msg_b * (deg>0)
// so the edge-space GEMM (800k x 96 x 64) collapses to node-space (50k x 96 x 64).

constexpr int N_NODES  = 50000;
constexpr int N_EDGES  = 800000;
constexpr int IN_DIM   = 64;
constexpr int EDGE_DIM = 32;
constexpr int OUT_DIM  = 64;

// ---------------------------------------------------------------------------
// K1: scatter-add inputs into per-dst accumulators.
// 768 threads/block = 8 edges x 96 lanes. Lane k<64 handles x[src][k],
// k in [64,96) handles ea[e][k-64]. One deg atomic per edge.
// ---------------------------------------------------------------------------
__global__ __launch_bounds__(768) void scatter_k(
    const float* __restrict__ x, const int* __restrict__ ei,
    const float* __restrict__ ea, float* sum_x,
    float* sum_ea, float* deg)
{
    const int t  = threadIdx.x;
    const int el = t / 96;        // 0..7 (compile-time magic div)
    const int k  = t - el * 96;   // 0..95
    const int e  = blockIdx.x * 8 + el;
    if (e >= N_EDGES) return;

    const int dst = ei[N_EDGES + e];
    if (k < IN_DIM) {
        const int src = ei[e];
        atomicAdd(&sum_x[dst * IN_DIM + k], x[src * IN_DIM + k]);
        if (k == 0) atomicAdd(&deg[dst], 1.0f);
    } else {
        const int kk = k - IN_DIM;
        atomicAdd(&sum_ea[dst * EDGE_DIM + kk], ea[e * EDGE_DIM + kk]);
    }
}

// ---------------------------------------------------------------------------
// K2: per-node finalize. One wave per node; lane c owns output column c.
// Weight columns live in registers (96 + 64 fp32). Node-row reads are
// wave-uniform (readfirstlane) -> scalar/broadcast loads.
// NOTE: sum_x_in aliases out (d_out reused). Each row is read+written only by
// its owning wave, and the store depends on the loads, so ordering is safe.
// ---------------------------------------------------------------------------
__global__ __launch_bounds__(256) void finalize_k(
    const float* __restrict__ x, const float* sum_x_in,
    const float* __restrict__ sum_ea, const float* __restrict__ deg,
    const float* __restrict__ msg_w, const float* __restrict__ msg_b,
    const float* __restrict__ self_w, const float* __restrict__ self_b,
    float* out)
{
    const int c = threadIdx.x & 63;

    float wm[96];   // msg_w column c
    float wsf[64];  // self_w column c
#pragma unroll
    for (int k = 0; k < 96; ++k) wm[k] = msg_w[k * OUT_DIM + c];
#pragma unroll
    for (int k = 0; k < 64; ++k) wsf[k] = self_w[k * OUT_DIM + c];
    const float mb = msg_b[c];
    const float sb = self_b[c];

    const int wave   = (blockIdx.x * blockDim.x + threadIdx.x) >> 6;
    const int nwaves = (gridDim.x * blockDim.x) >> 6;

    for (int n0 = wave; n0 < N_NODES; n0 += nwaves) {
        const int n = __builtin_amdgcn_readfirstlane(n0);

        const float d    = deg[n];
        const float inv  = 1.0f / fmaxf(d, 1.0f);
        const float bsel = (d > 0.0f) ? 1.0f : 0.0f;

        float am = 0.0f;  // message-space accumulator (pre-scale)
        float as = 0.0f;  // self accumulator
#pragma unroll
        for (int k = 0; k < 64; ++k)
            am = fmaf(sum_x_in[n * IN_DIM + k], wm[k], am);
#pragma unroll
        for (int k = 0; k < 32; ++k)
            am = fmaf(sum_ea[n * EDGE_DIM + k], wm[64 + k], am);
#pragma unroll
        for (int k = 0; k < 64; ++k)
            as = fmaf(x[n * IN_DIM + k], wsf[k], as);

        out[n * OUT_DIM + c] = as + sb + am * inv + mb * bsel;
    }
}

// ---------------------------------------------------------------------------
extern "C" void kernel_launch(void* const* d_in, const int* in_sizes, int n_in,
                              void* d_out, int out_size, void* d_ws, size_t ws_size,
                              hipStream_t stream) {
    const float* x      = (const float*)d_in[0];
    const int*   ei     = (const int*)d_in[1];   // [2][E], int32
    const float* ea     = (const float*)d_in[2];
    const float* msg_w  = (const float*)d_in[3]; // [96][64]
    const float* msg_b  = (const float*)d_in[4]; // [64]
    const float* self_w = (const float*)d_in[5]; // [64][64]
    const float* self_b = (const float*)d_in[6]; // [64]

    float* out    = (float*)d_out;                       // doubles as sum_x
    float* sum_ea = (float*)d_ws;                        // [N][32]
    float* deg    = sum_ea + (size_t)N_NODES * EDGE_DIM; // [N]

    // zero accumulators (harness poisons d_out / d_ws with 0xAA)
    hipMemsetAsync(d_out, 0, (size_t)N_NODES * OUT_DIM * sizeof(float), stream);
    hipMemsetAsync(d_ws, 0, (size_t)N_NODES * (EDGE_DIM + 1) * sizeof(float), stream);

    scatter_k<<<(N_EDGES + 7) / 8, 768, 0, stream>>>(x, ei, ea, out, sum_ea, deg);
    finalize_k<<<512, 256, 0, stream>>>(x, out, sum_ea, deg,
                                        msg_w, msg_b, self_w, self_b, out);
}

// Round 2
// 404.652 us; speedup vs baseline: 1.3153x; 1.3153x over previous
//
#include <hip/hip_runtime.h>

// EdgeSageLayer on MI355X — round 2.
// agg[n] = (sum_{e:dst=n} concat(x[src_e], ea_e)) @ msg_w / deg + msg_b*(deg>0)
// R1 showed fp32 atomic scatter is write-through (325 MB WRITE_SIZE, 360 us).
// R2: build CSR on the fly (int atomics only), then gather-reduce per node
// with coalesced row reads and plain stores.

constexpr int N_NODES  = 50000;
constexpr int N_EDGES  = 800000;
constexpr int IN_DIM   = 64;
constexpr int EDGE_DIM = 32;
constexpr int OUT_DIM  = 64;

// ---------------------------------------------------------------------------
// K1: histogram of dst into cnt[] (int atomics, 200 KB hot region).
// ---------------------------------------------------------------------------
__global__ __launch_bounds__(256) void count_k(const int* __restrict__ ei,
                                               int* cnt) {
    const int e = blockIdx.x * 256 + threadIdx.x;
    if (e < N_EDGES) atomicAdd(&cnt[ei[N_EDGES + e]], 1);
}

// ---------------------------------------------------------------------------
// K2: allocate contiguous ranges. Wave-scan of cnt, one atomic per wave on a
// global cursor (node order in perm is irrelevant, so no full scan needed).
// Stores cur[n] = exclusive offset (K3 bumps it; K4 recovers start=cur-cnt).
// ---------------------------------------------------------------------------
__global__ __launch_bounds__(256) void alloc_k(const int* __restrict__ cnt,
                                               int* cur, int* cursor) {
    const int n    = blockIdx.x * 256 + threadIdx.x;
    const int lane = threadIdx.x & 63;
    const int c    = (n < N_NODES) ? cnt[n] : 0;

    int v = c;  // inclusive wave scan
#pragma unroll
    for (int d = 1; d < 64; d <<= 1) {
        int t = __shfl_up(v, d);
        if (lane >= d) v += t;
    }
    const int total = __shfl(v, 63);
    int base = 0;
    if (lane == 0) base = atomicAdd(cursor, total);
    base = __shfl(base, 0);
    if (n < N_NODES) cur[n] = base + v - c;
}

// ---------------------------------------------------------------------------
// K3: place edge ids into perm at their node's slot.
// ---------------------------------------------------------------------------
__global__ __launch_bounds__(256) void place_k(const int* __restrict__ ei,
                                               int* cur, int* __restrict__ perm) {
    const int e = blockIdx.x * 256 + threadIdx.x;
    if (e < N_EDGES) {
        const int dst = ei[N_EDGES + e];
        const int pos = atomicAdd(&cur[dst], 1);
        perm[pos] = e;
    }
}

// ---------------------------------------------------------------------------
// K4: one wave per node. Lane c accumulates sum_x[n][c] (c<64) and
// sum_ea[n][c] (c<32) over the node's edge list. Coalesced row reads, plain
// stores, no atomics. 1-deep prefetch of the perm->ei dependent chain.
// ---------------------------------------------------------------------------
__global__ __launch_bounds__(256) void aggregate_k(
    const float* __restrict__ x, const int* __restrict__ ei,
    const float* __restrict__ ea, const int* __restrict__ perm,
    const int* __restrict__ cnt, const int* __restrict__ cur,
    float* __restrict__ sum_x, float* __restrict__ sum_ea)
{
    const int lane   = threadIdx.x & 63;
    const int wave   = (blockIdx.x * blockDim.x + threadIdx.x) >> 6;
    const int nwaves = (gridDim.x * blockDim.x) >> 6;

    for (int n0 = wave; n0 < N_NODES; n0 += nwaves) {
        const int n = __builtin_amdgcn_readfirstlane(n0);
        const int c = __builtin_amdgcn_readfirstlane(cnt[n]);
        const int s = __builtin_amdgcn_readfirstlane(cur[n]) - c;

        float sx = 0.0f, se = 0.0f;
        if (c > 0) {
            int e   = __builtin_amdgcn_readfirstlane(perm[s]);
            int src = __builtin_amdgcn_readfirstlane(ei[e]);
            for (int j = 0; j < c; ++j) {
                int e_n = 0, src_n = 0;
                if (j + 1 < c) {
                    e_n   = __builtin_amdgcn_readfirstlane(perm[s + j + 1]);
                    src_n = __builtin_amdgcn_readfirstlane(ei[e_n]);
                }
                sx += x[(size_t)src * IN_DIM + lane];
                if (lane < EDGE_DIM) se += ea[(size_t)e * EDGE_DIM + lane];
                e = e_n; src = src_n;
            }
        }
        sum_x[(size_t)n * IN_DIM + lane] = sx;
        if (lane < EDGE_DIM) sum_ea[(size_t)n * EDGE_DIM + lane] = se;
    }
}

// ---------------------------------------------------------------------------
// K5: per-node finalize (same as R1 but integer degree). Wave per node,
// lane c owns output column c; weight columns in registers.
// sum_x_in aliases out — each row read+written only by its owning wave.
// ---------------------------------------------------------------------------
__global__ __launch_bounds__(256) void finalize_k(
    const float* __restrict__ x, const float* sum_x_in,
    const float* __restrict__ sum_ea, const int* __restrict__ cnt,
    const float* __restrict__ msg_w, const float* __restrict__ msg_b,
    const float* __restrict__ self_w, const float* __restrict__ self_b,
    float* out)
{
    const int c = threadIdx.x & 63;

    float wm[96];   // msg_w column c
    float wsf[64];  // self_w column c
#pragma unroll
    for (int k = 0; k < 96; ++k) wm[k] = msg_w[k * OUT_DIM + c];
#pragma unroll
    for (int k = 0; k < 64; ++k) wsf[k] = self_w[k * OUT_DIM + c];
    const float mb = msg_b[c];
    const float sb = self_b[c];

    const int wave   = (blockIdx.x * blockDim.x + threadIdx.x) >> 6;
    const int nwaves = (gridDim.x * blockDim.x) >> 6;

    for (int n0 = wave; n0 < N_NODES; n0 += nwaves) {
        const int n = __builtin_amdgcn_readfirstlane(n0);

        const int   d    = cnt[n];
        const float inv  = 1.0f / (float)max(d, 1);
        const float bsel = (d > 0) ? 1.0f : 0.0f;

        float am = 0.0f, as = 0.0f;
#pragma unroll
        for (int k = 0; k < 64; ++k)
            am = fmaf(sum_x_in[n * IN_DIM + k], wm[k], am);
#pragma unroll
        for (int k = 0; k < 32; ++k)
            am = fmaf(sum_ea[n * EDGE_DIM + k], wm[64 + k], am);
#pragma unroll
        for (int k = 0; k < 64; ++k)
            as = fmaf(x[n * IN_DIM + k], wsf[k], as);

        out[n * OUT_DIM + c] = as + sb + am * inv + mb * bsel;
    }
}

// ---------------------------------------------------------------------------
// Fallback (R1 path) if ws is too small for CSR: atomic scatter, int degree.
// ---------------------------------------------------------------------------
__global__ __launch_bounds__(768) void scatter_fb_k(
    const float* __restrict__ x, const int* __restrict__ ei,
    const float* __restrict__ ea, float* sum_x, float* sum_ea, int* deg)
{
    const int t  = threadIdx.x;
    const int el = t / 96;
    const int k  = t - el * 96;
    const int e  = blockIdx.x * 8 + el;
    if (e >= N_EDGES) return;
    const int dst = ei[N_EDGES + e];
    if (k < IN_DIM) {
        const int src = ei[e];
        atomicAdd(&sum_x[dst * IN_DIM + k], x[src * IN_DIM + k]);
        if (k == 0) atomicAdd(&deg[dst], 1);
    } else {
        const int kk = k - IN_DIM;
        atomicAdd(&sum_ea[dst * EDGE_DIM + kk], ea[e * EDGE_DIM + kk]);
    }
}

// ---------------------------------------------------------------------------
extern "C" void kernel_launch(void* const* d_in, const int* in_sizes, int n_in,
                              void* d_out, int out_size, void* d_ws, size_t ws_size,
                              hipStream_t stream) {
    const float* x      = (const float*)d_in[0];
    const int*   ei     = (const int*)d_in[1];   // [2][E]
    const float* ea     = (const float*)d_in[2];
    const float* msg_w  = (const float*)d_in[3];
    const float* msg_b  = (const float*)d_in[4];
    const float* self_w = (const float*)d_in[5];
    const float* self_b = (const float*)d_in[6];

    float* out = (float*)d_out;  // doubles as sum_x accumulator

    // ws layout (elements): sum_ea[1.6M] | cnt[50k] | cur[50k] | perm[800k] | cursor[1]
    float* sum_ea = (float*)d_ws;
    int*   cnt    = (int*)(sum_ea + (size_t)N_NODES * EDGE_DIM);
    int*   cur    = cnt + N_NODES;
    int*   perm   = cur + N_NODES;
    int*   cursor = perm + N_EDGES;
    const size_t needed =
        ((size_t)N_NODES * EDGE_DIM + 2 * N_NODES + N_EDGES + 1) * sizeof(float);

    if (ws_size >= needed) {
        // zero cnt + cursor only (cur/perm/sums are fully overwritten)
        hipMemsetAsync(cnt, 0, N_NODES * sizeof(int), stream);
        hipMemsetAsync(cursor, 0, sizeof(int), stream);

        count_k<<<(N_EDGES + 255) / 256, 256, 0, stream>>>(ei, cnt);
        alloc_k<<<(N_NODES + 255) / 256, 256, 0, stream>>>(cnt, cur, cursor);
        place_k<<<(N_EDGES + 255) / 256, 256, 0, stream>>>(ei, cur, perm);
        aggregate_k<<<(N_NODES + 3) / 4, 256, 0, stream>>>(
            x, ei, ea, perm, cnt, cur, out, sum_ea);
        finalize_k<<<512, 256, 0, stream>>>(x, out, sum_ea, cnt,
                                            msg_w, msg_b, self_w, self_b, out);
    } else {
        // R1 fallback: atomic scatter
        int* deg = (int*)(sum_ea + (size_t)N_NODES * EDGE_DIM);
        hipMemsetAsync(d_out, 0, (size_t)N_NODES * OUT_DIM * sizeof(float), stream);
        hipMemsetAsync(d_ws, 0, (size_t)N_NODES * (EDGE_DIM + 1) * sizeof(float), stream);
        scatter_fb_k<<<(N_EDGES + 7) / 8, 768, 0, stream>>>(x, ei, ea, out, sum_ea, deg);
        finalize_k<<<512, 256, 0, stream>>>(x, out, sum_ea, deg,
                                            msg_w, msg_b, self_w, self_b, out);
    }
}

// Round 3
// 394.944 us; speedup vs baseline: 1.3476x; 1.0246x over previous
//
#include <hip/hip_runtime.h>

// EdgeSageLayer on MI355X — round 3.
// agg[n] = (sum_{e:dst=n} concat(x[src_e], ea_e)) @ msg_w / deg + msg_b*(deg>0)
// R2: CSR gather-reduce worked (WRITE 325->19 MB) but aggregate_k was
// latency-bound (1.57 TB/s, VALU 5%): per-edge dependent scalar chain +
// 1 wave-instr per 256 B row. R3: batch index gather (64 edges / 2 loads),
// float4 payload (4 x-rows or 8 ea-rows per instruction), shfl_xor reduce.

constexpr int N_NODES  = 50000;
constexpr int N_EDGES  = 800000;
constexpr int IN_DIM   = 64;
constexpr int EDGE_DIM = 32;
constexpr int OUT_DIM  = 64;

// ---------------------------------------------------------------------------
// K1: histogram of dst (int atomics into 200 KB region), int4 edge reads.
// ---------------------------------------------------------------------------
__global__ __launch_bounds__(256) void count_k(const int* __restrict__ ei,
                                               int* cnt) {
    const int t = blockIdx.x * 256 + threadIdx.x;
    if (t * 4 + 3 < N_EDGES) {
        const int4 d4 = ((const int4*)(ei + N_EDGES))[t];
        atomicAdd(&cnt[d4.x], 1);
        atomicAdd(&cnt[d4.y], 1);
        atomicAdd(&cnt[d4.z], 1);
        atomicAdd(&cnt[d4.w], 1);
    } else {
        for (int e = t * 4; e < min(t * 4 + 4, N_EDGES); ++e)
            atomicAdd(&cnt[ei[N_EDGES + e]], 1);
    }
}

// ---------------------------------------------------------------------------
// K2: allocate contiguous ranges: wave scan + one global-cursor atomic/wave.
// cur[n] = exclusive start (K3 bumps it; K4 recovers start = cur - cnt).
// ---------------------------------------------------------------------------
__global__ __launch_bounds__(256) void alloc_k(const int* __restrict__ cnt,
                                               int* cur, int* cursor) {
    const int n    = blockIdx.x * 256 + threadIdx.x;
    const int lane = threadIdx.x & 63;
    const int c    = (n < N_NODES) ? cnt[n] : 0;

    int v = c;
#pragma unroll
    for (int d = 1; d < 64; d <<= 1) {
        int t = __shfl_up(v, d);
        if (lane >= d) v += t;
    }
    const int total = __shfl(v, 63);
    int base = 0;
    if (lane == 0) base = atomicAdd(cursor, total);
    base = __shfl(base, 0);
    if (n < N_NODES) cur[n] = base + v - c;
}

// ---------------------------------------------------------------------------
// K3: place edge ids into perm, int4 edge reads.
// ---------------------------------------------------------------------------
__global__ __launch_bounds__(256) void place_k(const int* __restrict__ ei,
                                               int* cur, int* __restrict__ perm) {
    const int t = blockIdx.x * 256 + threadIdx.x;
    if (t * 4 + 3 < N_EDGES) {
        const int4 d4 = ((const int4*)(ei + N_EDGES))[t];
        perm[atomicAdd(&cur[d4.x], 1)] = t * 4 + 0;
        perm[atomicAdd(&cur[d4.y], 1)] = t * 4 + 1;
        perm[atomicAdd(&cur[d4.z], 1)] = t * 4 + 2;
        perm[atomicAdd(&cur[d4.w], 1)] = t * 4 + 3;
    } else {
        for (int e = t * 4; e < min(t * 4 + 4, N_EDGES); ++e)
            perm[atomicAdd(&cur[ei[N_EDGES + e]], 1)] = e;
    }
}

// ---------------------------------------------------------------------------
// K4: one wave per node, vectorized gather-reduce.
//  - batch: up to 64 edge ids + src ids fetched in 2 parallel vector loads
//  - x rows: float4, 16 lanes/row -> 4 edges per dwordx4 instruction
//  - ea rows: float4, 8 lanes/row -> 8 edges per instruction
//  - shfl_xor cross-group reduce; float4 stores (also zero-fills deg==0 rows,
//    so no memset of the sum buffers is needed).
// ---------------------------------------------------------------------------
__global__ __launch_bounds__(256) void aggregate_k(
    const float* __restrict__ x, const int* __restrict__ ei,
    const float* __restrict__ ea, const int* __restrict__ perm,
    const int* __restrict__ cnt, const int* __restrict__ cur,
    float* __restrict__ sum_x, float* __restrict__ sum_ea)
{
    const int lane   = threadIdx.x & 63;
    const int wave   = (blockIdx.x * blockDim.x + threadIdx.x) >> 6;
    const int nwaves = (gridDim.x * blockDim.x) >> 6;

    const int grpx = lane >> 4, colx = lane & 15;  // x: 4 edges / step
    const int grpe = lane >> 3, cole = lane & 7;   // ea: 8 edges / step

    for (int n0 = wave; n0 < N_NODES; n0 += nwaves) {
        const int n = __builtin_amdgcn_readfirstlane(n0);
        const int c = __builtin_amdgcn_readfirstlane(cnt[n]);
        const int s = __builtin_amdgcn_readfirstlane(cur[n]) - c;

        float4 ax = {0.f, 0.f, 0.f, 0.f};
        float4 ae = {0.f, 0.f, 0.f, 0.f};

        for (int base = 0; base < c; base += 64) {
            const int m = min(64, c - base);
            int e = 0, src = 0;
            if (lane < m) {
                e   = perm[s + base + lane];
                src = ei[e];
            }
            for (int j = 0; j < m; j += 4) {
                const int jj = j + grpx;
                const int sj = __shfl(src, jj);
                if (jj < m) {
                    const float4 v =
                        ((const float4*)(x + (size_t)sj * IN_DIM))[colx];
                    ax.x += v.x; ax.y += v.y; ax.z += v.z; ax.w += v.w;
                }
            }
            for (int j = 0; j < m; j += 8) {
                const int jj = j + grpe;
                const int ej = __shfl(e, jj);
                if (jj < m) {
                    const float4 v =
                        ((const float4*)(ea + (size_t)ej * EDGE_DIM))[cole];
                    ae.x += v.x; ae.y += v.y; ae.z += v.z; ae.w += v.w;
                }
            }
        }

#pragma unroll
        for (int mask = 16; mask < 64; mask <<= 1) {
            ax.x += __shfl_xor(ax.x, mask);
            ax.y += __shfl_xor(ax.y, mask);
            ax.z += __shfl_xor(ax.z, mask);
            ax.w += __shfl_xor(ax.w, mask);
        }
#pragma unroll
        for (int mask = 8; mask < 64; mask <<= 1) {
            ae.x += __shfl_xor(ae.x, mask);
            ae.y += __shfl_xor(ae.y, mask);
            ae.z += __shfl_xor(ae.z, mask);
            ae.w += __shfl_xor(ae.w, mask);
        }

        if (lane < 16) ((float4*)(sum_x + (size_t)n * IN_DIM))[lane] = ax;
        if (lane < 8)  ((float4*)(sum_ea + (size_t)n * EDGE_DIM))[lane] = ae;
    }
}

// ---------------------------------------------------------------------------
// K5: per-node finalize. Wave per node; lane c owns output column c; weight
// columns in registers. The three input rows are loaded ONCE per node as
// coalesced per-lane values and broadcast via shfl (pure VALU k-loop — no
// per-k broadcast VMEM loads, no aliasing hazard).
// ---------------------------------------------------------------------------
__global__ __launch_bounds__(256) void finalize_k(
    const float* __restrict__ x, const float* sum_x_in,
    const float* __restrict__ sum_ea, const int* __restrict__ cnt,
    const float* __restrict__ msg_w, const float* __restrict__ msg_b,
    const float* __restrict__ self_w, const float* __restrict__ self_b,
    float* out)
{
    const int c = threadIdx.x & 63;

    float wm[96];   // msg_w column c
    float wsf[64];  // self_w column c
#pragma unroll
    for (int k = 0; k < 96; ++k) wm[k] = msg_w[k * OUT_DIM + c];
#pragma unroll
    for (int k = 0; k < 64; ++k) wsf[k] = self_w[k * OUT_DIM + c];
    const float mb = msg_b[c];
    const float sb = self_b[c];

    const int wave   = (blockIdx.x * blockDim.x + threadIdx.x) >> 6;
    const int nwaves = (gridDim.x * blockDim.x) >> 6;

    for (int n0 = wave; n0 < N_NODES; n0 += nwaves) {
        const int n = __builtin_amdgcn_readfirstlane(n0);

        const float v1 = sum_x_in[(size_t)n * IN_DIM + c];                    // lane c = col c
        const float v2 = (c < EDGE_DIM) ? sum_ea[(size_t)n * EDGE_DIM + c] : 0.f;
        const float v3 = x[(size_t)n * IN_DIM + c];
        const int   d  = cnt[n];

        const float inv  = 1.0f / (float)max(d, 1);
        const float bsel = (d > 0) ? 1.0f : 0.0f;

        float am = 0.0f, as = 0.0f;
#pragma unroll
        for (int k = 0; k < 64; ++k) am = fmaf(__shfl(v1, k), wm[k], am);
#pragma unroll
        for (int k = 0; k < 32; ++k) am = fmaf(__shfl(v2, k), wm[64 + k], am);
#pragma unroll
        for (int k = 0; k < 64; ++k) as = fmaf(__shfl(v3, k), wsf[k], as);

        out[(size_t)n * OUT_DIM + c] = as + sb + am * inv + mb * bsel;
    }
}

// ---------------------------------------------------------------------------
// Fallback (atomic scatter) if ws is too small for CSR.
// ---------------------------------------------------------------------------
__global__ __launch_bounds__(768) void scatter_fb_k(
    const float* __restrict__ x, const int* __restrict__ ei,
    const float* __restrict__ ea, float* sum_x, float* sum_ea, int* deg)
{
    const int t  = threadIdx.x;
    const int el = t / 96;
    const int k  = t - el * 96;
    const int e  = blockIdx.x * 8 + el;
    if (e >= N_EDGES) return;
    const int dst = ei[N_EDGES + e];
    if (k < IN_DIM) {
        const int src = ei[e];
        atomicAdd(&sum_x[dst * IN_DIM + k], x[src * IN_DIM + k]);
        if (k == 0) atomicAdd(&deg[dst], 1);
    } else {
        const int kk = k - IN_DIM;
        atomicAdd(&sum_ea[dst * EDGE_DIM + kk], ea[e * EDGE_DIM + kk]);
    }
}

// ---------------------------------------------------------------------------
extern "C" void kernel_launch(void* const* d_in, const int* in_sizes, int n_in,
                              void* d_out, int out_size, void* d_ws, size_t ws_size,
                              hipStream_t stream) {
    const float* x      = (const float*)d_in[0];
    const int*   ei     = (const int*)d_in[1];   // [2][E]
    const float* ea     = (const float*)d_in[2];
    const float* msg_w  = (const float*)d_in[3];
    const float* msg_b  = (const float*)d_in[4];
    const float* self_w = (const float*)d_in[5];
    const float* self_b = (const float*)d_in[6];

    float* out = (float*)d_out;  // doubles as sum_x accumulator

    // ws layout (elements): sum_ea[1.6M] | cnt[50k] | cur[50k] | perm[800k] | cursor[1]
    float* sum_ea = (float*)d_ws;
    int*   cnt    = (int*)(sum_ea + (size_t)N_NODES * EDGE_DIM);
    int*   cur    = cnt + N_NODES;
    int*   perm   = cur + N_NODES;
    int*   cursor = perm + N_EDGES;
    const size_t needed =
        ((size_t)N_NODES * EDGE_DIM + 2 * N_NODES + N_EDGES + 1) * sizeof(float);

    if (ws_size >= needed) {
        hipMemsetAsync(cnt, 0, N_NODES * sizeof(int), stream);
        hipMemsetAsync(cursor, 0, sizeof(int), stream);

        count_k<<<(N_EDGES / 4 + 255) / 256, 256, 0, stream>>>(ei, cnt);
        alloc_k<<<(N_NODES + 255) / 256, 256, 0, stream>>>(cnt, cur, cursor);
        place_k<<<(N_EDGES / 4 + 255) / 256, 256, 0, stream>>>(ei, cur, perm);
        aggregate_k<<<(N_NODES + 3) / 4, 256, 0, stream>>>(
            x, ei, ea, perm, cnt, cur, out, sum_ea);
        finalize_k<<<512, 256, 0, stream>>>(x, out, sum_ea, cnt,
                                            msg_w, msg_b, self_w, self_b, out);
    } else {
        int* deg = (int*)(sum_ea + (size_t)N_NODES * EDGE_DIM);
        hipMemsetAsync(d_out, 0, (size_t)N_NODES * OUT_DIM * sizeof(float), stream);
        hipMemsetAsync(d_ws, 0, (size_t)N_NODES * (EDGE_DIM + 1) * sizeof(float), stream);
        scatter_fb_k<<<(N_EDGES + 7) / 8, 768, 0, stream>>>(x, ei, ea, out, sum_ea, deg);
        finalize_k<<<512, 256, 0, stream>>>(x, out, sum_ea, deg,
                                            msg_w, msg_b, self_w, self_b, out);
    }
}

// Round 4
// 345.493 us; speedup vs baseline: 1.5405x; 1.1431x over previous
//
#include <hip/hip_runtime.h>

// EdgeSageLayer on MI355X — round 4.
// agg[n] = (sum_{e:dst=n} concat(x[src_e], ea_e)) @ msg_w / deg + msg_b*(deg>0)
// R3 postmortem: finalize_k was 102 us — shfl-broadcast (LDS pipe) + serial
// fma chain + grid too small. R4 finalize: float4 broadcast VMEM row loads,
// 4-way split accumulators, 1024 blocks. aggregate: 2 nodes in flight per
// wave to cover the perm->ei->payload latency chain.

constexpr int N_NODES  = 50000;
constexpr int N_EDGES  = 800000;
constexpr int IN_DIM   = 64;
constexpr int EDGE_DIM = 32;
constexpr int OUT_DIM  = 64;

// ---------------------------------------------------------------------------
// K1: histogram of dst (int atomics into 200 KB region), int4 edge reads.
// ---------------------------------------------------------------------------
__global__ __launch_bounds__(256) void count_k(const int* __restrict__ ei,
                                               int* cnt) {
    const int t = blockIdx.x * 256 + threadIdx.x;
    if (t * 4 + 3 < N_EDGES) {
        const int4 d4 = ((const int4*)(ei + N_EDGES))[t];
        atomicAdd(&cnt[d4.x], 1);
        atomicAdd(&cnt[d4.y], 1);
        atomicAdd(&cnt[d4.z], 1);
        atomicAdd(&cnt[d4.w], 1);
    } else {
        for (int e = t * 4; e < min(t * 4 + 4, N_EDGES); ++e)
            atomicAdd(&cnt[ei[N_EDGES + e]], 1);
    }
}

// ---------------------------------------------------------------------------
// K2: allocate contiguous ranges: wave scan + one global-cursor atomic/wave.
// cur[n] = exclusive start (K3 bumps it; K4 recovers start = cur - cnt).
// ---------------------------------------------------------------------------
__global__ __launch_bounds__(256) void alloc_k(const int* __restrict__ cnt,
                                               int* cur, int* cursor) {
    const int n    = blockIdx.x * 256 + threadIdx.x;
    const int lane = threadIdx.x & 63;
    const int c    = (n < N_NODES) ? cnt[n] : 0;

    int v = c;
#pragma unroll
    for (int d = 1; d < 64; d <<= 1) {
        int t = __shfl_up(v, d);
        if (lane >= d) v += t;
    }
    const int total = __shfl(v, 63);
    int base = 0;
    if (lane == 0) base = atomicAdd(cursor, total);
    base = __shfl(base, 0);
    if (n < N_NODES) cur[n] = base + v - c;
}

// ---------------------------------------------------------------------------
// K3: place edge ids into perm, int4 edge reads.
// ---------------------------------------------------------------------------
__global__ __launch_bounds__(256) void place_k(const int* __restrict__ ei,
                                               int* cur, int* __restrict__ perm) {
    const int t = blockIdx.x * 256 + threadIdx.x;
    if (t * 4 + 3 < N_EDGES) {
        const int4 d4 = ((const int4*)(ei + N_EDGES))[t];
        perm[atomicAdd(&cur[d4.x], 1)] = t * 4 + 0;
        perm[atomicAdd(&cur[d4.y], 1)] = t * 4 + 1;
        perm[atomicAdd(&cur[d4.z], 1)] = t * 4 + 2;
        perm[atomicAdd(&cur[d4.w], 1)] = t * 4 + 3;
    } else {
        for (int e = t * 4; e < min(t * 4 + 4, N_EDGES); ++e)
            perm[atomicAdd(&cur[ei[N_EDGES + e]], 1)] = e;
    }
}

// ---------------------------------------------------------------------------
// helper: accumulate one <=64-edge batch of node n (s=CSR start) into ax/ae.
// ---------------------------------------------------------------------------
__device__ __forceinline__ void gather_batch(
    const float* __restrict__ x, const float* __restrict__ ea,
    const int* __restrict__ ei, const int* __restrict__ perm,
    int s, int base, int m, int lane, int grpx, int colx, int grpe, int cole,
    float4& ax, float4& ae)
{
    int e = 0, src = 0;
    if (lane < m) { e = perm[s + base + lane]; src = ei[e]; }
    for (int j = 0; j < m; j += 4) {
        const int jj = j + grpx;
        const int sj = __shfl(src, jj);
        if (jj < m) {
            const float4 v = ((const float4*)(x + (size_t)sj * IN_DIM))[colx];
            ax.x += v.x; ax.y += v.y; ax.z += v.z; ax.w += v.w;
        }
    }
    for (int j = 0; j < m; j += 8) {
        const int jj = j + grpe;
        const int ej = __shfl(e, jj);
        if (jj < m) {
            const float4 v = ((const float4*)(ea + (size_t)ej * EDGE_DIM))[cole];
            ae.x += v.x; ae.y += v.y; ae.z += v.z; ae.w += v.w;
        }
    }
}

// ---------------------------------------------------------------------------
// K4: gather-reduce, TWO nodes in flight per wave (independent latency
// chains). x rows: float4 x 16 lanes (4 edges/instr); ea: float4 x 8 lanes
// (8 edges/instr); shfl_xor reduce; float4 stores (zero-fills deg==0 rows).
// Rare deg>64 handled by a cleanup batch loop.
// ---------------------------------------------------------------------------
__global__ __launch_bounds__(256) void aggregate_k(
    const float* __restrict__ x, const int* __restrict__ ei,
    const float* __restrict__ ea, const int* __restrict__ perm,
    const int* __restrict__ cnt, const int* __restrict__ cur,
    float* __restrict__ sum_x, float* __restrict__ sum_ea)
{
    const int lane   = threadIdx.x & 63;
    const int wave   = (blockIdx.x * blockDim.x + threadIdx.x) >> 6;
    const int nwaves = (gridDim.x * blockDim.x) >> 6;

    const int grpx = lane >> 4, colx = lane & 15;
    const int grpe = lane >> 3, cole = lane & 7;

    for (int n0 = wave * 2; n0 < N_NODES; n0 += nwaves * 2) {
        const int  nA   = __builtin_amdgcn_readfirstlane(n0);
        const bool hasB = (n0 + 1 < N_NODES);
        const int  nB   = nA + 1;

        const int cA = __builtin_amdgcn_readfirstlane(cnt[nA]);
        const int sA = __builtin_amdgcn_readfirstlane(cur[nA]) - cA;
        const int cB = hasB ? __builtin_amdgcn_readfirstlane(cnt[nB]) : 0;
        const int sB = hasB ? __builtin_amdgcn_readfirstlane(cur[nB]) - cB : 0;

        const int mA = min(cA, 64), mB = min(cB, 64);

        // index batches for both nodes (independent dependent-chains)
        int eA = 0, srcA = 0, eB = 0, srcB = 0;
        if (lane < mA) eA = perm[sA + lane];
        if (lane < mB) eB = perm[sB + lane];
        if (lane < mA) srcA = ei[eA];
        if (lane < mB) srcB = ei[eB];

        float4 axA = {0,0,0,0}, aeA = {0,0,0,0};
        float4 axB = {0,0,0,0}, aeB = {0,0,0,0};

        const int mMax = max(mA, mB);
        for (int j = 0; j < mMax; j += 4) {
            const int jj  = j + grpx;
            const int sjA = __shfl(srcA, jj);
            const int sjB = __shfl(srcB, jj);
            if (jj < mA) {
                const float4 v = ((const float4*)(x + (size_t)sjA * IN_DIM))[colx];
                axA.x += v.x; axA.y += v.y; axA.z += v.z; axA.w += v.w;
            }
            if (jj < mB) {
                const float4 v = ((const float4*)(x + (size_t)sjB * IN_DIM))[colx];
                axB.x += v.x; axB.y += v.y; axB.z += v.z; axB.w += v.w;
            }
        }
        for (int j = 0; j < mMax; j += 8) {
            const int jj  = j + grpe;
            const int ejA = __shfl(eA, jj);
            const int ejB = __shfl(eB, jj);
            if (jj < mA) {
                const float4 v = ((const float4*)(ea + (size_t)ejA * EDGE_DIM))[cole];
                aeA.x += v.x; aeA.y += v.y; aeA.z += v.z; aeA.w += v.w;
            }
            if (jj < mB) {
                const float4 v = ((const float4*)(ea + (size_t)ejB * EDGE_DIM))[cole];
                aeB.x += v.x; aeB.y += v.y; aeB.z += v.z; aeB.w += v.w;
            }
        }

        // rare: deg > 64
        for (int base = 64; base < cA; base += 64)
            gather_batch(x, ea, ei, perm, sA, base, min(64, cA - base),
                         lane, grpx, colx, grpe, cole, axA, aeA);
        for (int base = 64; base < cB; base += 64)
            gather_batch(x, ea, ei, perm, sB, base, min(64, cB - base),
                         lane, grpx, colx, grpe, cole, axB, aeB);

#pragma unroll
        for (int mask = 16; mask < 64; mask <<= 1) {
            axA.x += __shfl_xor(axA.x, mask); axA.y += __shfl_xor(axA.y, mask);
            axA.z += __shfl_xor(axA.z, mask); axA.w += __shfl_xor(axA.w, mask);
            axB.x += __shfl_xor(axB.x, mask); axB.y += __shfl_xor(axB.y, mask);
            axB.z += __shfl_xor(axB.z, mask); axB.w += __shfl_xor(axB.w, mask);
        }
#pragma unroll
        for (int mask = 8; mask < 64; mask <<= 1) {
            aeA.x += __shfl_xor(aeA.x, mask); aeA.y += __shfl_xor(aeA.y, mask);
            aeA.z += __shfl_xor(aeA.z, mask); aeA.w += __shfl_xor(aeA.w, mask);
            aeB.x += __shfl_xor(aeB.x, mask); aeB.y += __shfl_xor(aeB.y, mask);
            aeB.z += __shfl_xor(aeB.z, mask); aeB.w += __shfl_xor(aeB.w, mask);
        }

        if (lane < 16) ((float4*)(sum_x + (size_t)nA * IN_DIM))[lane] = axA;
        if (lane < 8)  ((float4*)(sum_ea + (size_t)nA * EDGE_DIM))[lane] = aeA;
        if (hasB) {
            if (lane < 16) ((float4*)(sum_x + (size_t)nB * IN_DIM))[lane] = axB;
            if (lane < 8)  ((float4*)(sum_ea + (size_t)nB * EDGE_DIM))[lane] = aeB;
        }
    }
}

// ---------------------------------------------------------------------------
// K5: per-node finalize. Wave per node; lane c owns output column c; weight
// columns in registers. Row values are wave-uniform -> float4 broadcast VMEM
// loads (single L1 access each), 4-way split accumulators for ILP.
// sum_x_in aliases out (no __restrict__ on those two) — each row is
// read+written only by its owning wave; store depends on the loads.
// ---------------------------------------------------------------------------
__global__ __launch_bounds__(256) void finalize_k(
    const float* __restrict__ x, const float* sum_x_in,
    const float* __restrict__ sum_ea, const int* __restrict__ cnt,
    const float* __restrict__ msg_w, const float* __restrict__ msg_b,
    const float* __restrict__ self_w, const float* __restrict__ self_b,
    float* out)
{
    const int c = threadIdx.x & 63;

    float wm[96];   // msg_w column c
    float wsf[64];  // self_w column c
#pragma unroll
    for (int k = 0; k < 96; ++k) wm[k] = msg_w[k * OUT_DIM + c];
#pragma unroll
    for (int k = 0; k < 64; ++k) wsf[k] = self_w[k * OUT_DIM + c];
    const float mb = msg_b[c];
    const float sb = self_b[c];

    const int wave   = (blockIdx.x * blockDim.x + threadIdx.x) >> 6;
    const int nwaves = (gridDim.x * blockDim.x) >> 6;

    for (int n0 = wave; n0 < N_NODES; n0 += nwaves) {
        const int n = __builtin_amdgcn_readfirstlane(n0);

        const float4* r1 = (const float4*)(sum_x_in + (size_t)n * IN_DIM);
        const float4* r2 = (const float4*)(sum_ea   + (size_t)n * EDGE_DIM);
        const float4* r3 = (const float4*)(x        + (size_t)n * IN_DIM);
        const int d = cnt[n];

        float am0 = 0.f, am1 = 0.f, am2 = 0.f, am3 = 0.f;
        float as0 = 0.f, as1 = 0.f, as2 = 0.f, as3 = 0.f;
#pragma unroll
        for (int q = 0; q < 16; ++q) {
            const float4 v = r1[q];
            am0 = fmaf(v.x, wm[4 * q + 0], am0);
            am1 = fmaf(v.y, wm[4 * q + 1], am1);
            am2 = fmaf(v.z, wm[4 * q + 2], am2);
            am3 = fmaf(v.w, wm[4 * q + 3], am3);
        }
#pragma unroll
        for (int q = 0; q < 8; ++q) {
            const float4 v = r2[q];
            am0 = fmaf(v.x, wm[64 + 4 * q + 0], am0);
            am1 = fmaf(v.y, wm[64 + 4 * q + 1], am1);
            am2 = fmaf(v.z, wm[64 + 4 * q + 2], am2);
            am3 = fmaf(v.w, wm[64 + 4 * q + 3], am3);
        }
#pragma unroll
        for (int q = 0; q < 16; ++q) {
            const float4 v = r3[q];
            as0 = fmaf(v.x, wsf[4 * q + 0], as0);
            as1 = fmaf(v.y, wsf[4 * q + 1], as1);
            as2 = fmaf(v.z, wsf[4 * q + 2], as2);
            as3 = fmaf(v.w, wsf[4 * q + 3], as3);
        }

        const float inv  = 1.0f / (float)max(d, 1);
        const float bsel = (d > 0) ? 1.0f : 0.0f;
        const float am   = (am0 + am1) + (am2 + am3);
        const float as   = (as0 + as1) + (as2 + as3);

        out[(size_t)n * OUT_DIM + c] = as + sb + am * inv + mb * bsel;
    }
}

// ---------------------------------------------------------------------------
// Fallback (atomic scatter) if ws is too small for CSR.
// ---------------------------------------------------------------------------
__global__ __launch_bounds__(768) void scatter_fb_k(
    const float* __restrict__ x, const int* __restrict__ ei,
    const float* __restrict__ ea, float* sum_x, float* sum_ea, int* deg)
{
    const int t  = threadIdx.x;
    const int el = t / 96;
    const int k  = t - el * 96;
    const int e  = blockIdx.x * 8 + el;
    if (e >= N_EDGES) return;
    const int dst = ei[N_EDGES + e];
    if (k < IN_DIM) {
        const int src = ei[e];
        atomicAdd(&sum_x[dst * IN_DIM + k], x[src * IN_DIM + k]);
        if (k == 0) atomicAdd(&deg[dst], 1);
    } else {
        const int kk = k - IN_DIM;
        atomicAdd(&sum_ea[dst * EDGE_DIM + kk], ea[e * EDGE_DIM + kk]);
    }
}

// ---------------------------------------------------------------------------
extern "C" void kernel_launch(void* const* d_in, const int* in_sizes, int n_in,
                              void* d_out, int out_size, void* d_ws, size_t ws_size,
                              hipStream_t stream) {
    const float* x      = (const float*)d_in[0];
    const int*   ei     = (const int*)d_in[1];   // [2][E]
    const float* ea     = (const float*)d_in[2];
    const float* msg_w  = (const float*)d_in[3];
    const float* msg_b  = (const float*)d_in[4];
    const float* self_w = (const float*)d_in[5];
    const float* self_b = (const float*)d_in[6];

    float* out = (float*)d_out;  // doubles as sum_x accumulator

    // ws layout (elements): sum_ea[1.6M] | cnt[50k] | cur[50k] | perm[800k] | cursor[1]
    float* sum_ea = (float*)d_ws;
    int*   cnt    = (int*)(sum_ea + (size_t)N_NODES * EDGE_DIM);
    int*   cur    = cnt + N_NODES;
    int*   perm   = cur + N_NODES;
    int*   cursor = perm + N_EDGES;
    const size_t needed =
        ((size_t)N_NODES * EDGE_DIM + 2 * N_NODES + N_EDGES + 1) * sizeof(float);

    if (ws_size >= needed) {
        hipMemsetAsync(cnt, 0, N_NODES * sizeof(int), stream);
        hipMemsetAsync(cursor, 0, sizeof(int), stream);

        count_k<<<(N_EDGES / 4 + 255) / 256, 256, 0, stream>>>(ei, cnt);
        alloc_k<<<(N_NODES + 255) / 256, 256, 0, stream>>>(cnt, cur, cursor);
        place_k<<<(N_EDGES / 4 + 255) / 256, 256, 0, stream>>>(ei, cur, perm);
        aggregate_k<<<(N_NODES / 2 + 3) / 4, 256, 0, stream>>>(
            x, ei, ea, perm, cnt, cur, out, sum_ea);
        finalize_k<<<1024, 256, 0, stream>>>(x, out, sum_ea, cnt,
                                             msg_w, msg_b, self_w, self_b, out);
    } else {
        int* deg = (int*)(sum_ea + (size_t)N_NODES * EDGE_DIM);
        hipMemsetAsync(d_out, 0, (size_t)N_NODES * OUT_DIM * sizeof(float), stream);
        hipMemsetAsync(d_ws, 0, (size_t)N_NODES * (EDGE_DIM + 1) * sizeof(float), stream);
        scatter_fb_k<<<(N_EDGES + 7) / 8, 768, 0, stream>>>(x, ei, ea, out, sum_ea, deg);
        finalize_k<<<1024, 256, 0, stream>>>(x, out, sum_ea, (const int*)deg,
                                             msg_w, msg_b, self_w, self_b, out);
    }
}